// Round 2
// baseline (91758.606 us; speedup 1.0000x reference)
//
#include <hip/hip_runtime.h>
#include <hip/hip_bf16.h>
#include <math.h>

#define MAPNEGINF 0x007FFFFFu

__device__ __forceinline__ float geluf(float x) {
    return 0.5f * x * (1.0f + erff(x * 0.70710678118654752f));
}
__device__ __forceinline__ unsigned fmap(float f) {
    unsigned u = __float_as_uint(f);
    return ((int)u < 0) ? ~u : (u | 0x80000000u);
}
__device__ __forceinline__ float funmap(unsigned m) {
    return __uint_as_float((m & 0x80000000u) ? (m ^ 0x80000000u) : ~m);
}
__device__ __forceinline__ float wred64(float v) {
#pragma unroll
    for (int m = 1; m < 64; m <<= 1) v += __shfl_xor(v, m);
    return v;
}

// ---------------- GEMM tile helpers ----------------
// As: [64][132] f32 LDS (rows x K). Ws: [32][128] f32 LDS (K-quarter x out-cols).
// Thread (og=t&15, eg=t>>4) owns rows eg*4..+3, cols og*4..+3 and 64+og*4..+3.
__device__ __forceinline__ void stage_wq(float* Ws, const float* __restrict__ src, int t) {
#pragma unroll
    for (int it = 0; it < 4; ++it) {
        const int idx = it * 1024 + (t << 2);
        *(float4*)(Ws + idx) = *(const float4*)(src + idx);
    }
}

__device__ __forceinline__ void kloop_q(const float* As, const float* Ws, float (&acc)[4][8],
                                        const int r0, const int ogc, const int kb) {
#pragma unroll
    for (int kk = 0; kk < 32; kk += 4) {
        const float4 a0 = *(const float4*)(As + (r0 + 0) * 132 + kb + kk);
        const float4 a1 = *(const float4*)(As + (r0 + 1) * 132 + kb + kk);
        const float4 a2 = *(const float4*)(As + (r0 + 2) * 132 + kb + kk);
        const float4 a3 = *(const float4*)(As + (r0 + 3) * 132 + kb + kk);
#define MAD8(R, AV)                                                                     \
    {                                                                                   \
        acc[R][0] += (AV)*wA.x; acc[R][1] += (AV)*wA.y; acc[R][2] += (AV)*wA.z;         \
        acc[R][3] += (AV)*wA.w; acc[R][4] += (AV)*wB.x; acc[R][5] += (AV)*wB.y;         \
        acc[R][6] += (AV)*wB.z; acc[R][7] += (AV)*wB.w;                                 \
    }
#define KSTEP(J, C)                                                                     \
    {                                                                                   \
        const float4 wA = *(const float4*)(Ws + (kk + (J)) * 128 + ogc);                \
        const float4 wB = *(const float4*)(Ws + (kk + (J)) * 128 + 64 + ogc);           \
        MAD8(0, a0.C) MAD8(1, a1.C) MAD8(2, a2.C) MAD8(3, a3.C)                         \
    }
        KSTEP(0, x) KSTEP(1, y) KSTEP(2, z) KSTEP(3, w)
#undef KSTEP
#undef MAD8
    }
}

// ---------------- misc ----------------
__global__ void k_zero(unsigned* __restrict__ p, int n) {
    const int i = blockIdx.x * 256 + threadIdx.x;
    if (i < n) p[i] = 0u;
}

// ---------------- CSR build ----------------
__global__ void k_count(const int* __restrict__ ei, unsigned* __restrict__ deg, int E) {
    const int e = blockIdx.x * 256 + threadIdx.x;
    if (e < E) atomicAdd(deg + ei[E + e], 1u);
}

__global__ void k_scan1(const unsigned* __restrict__ deg, unsigned* __restrict__ excl,
                        unsigned* __restrict__ bsum, int n) {
    __shared__ unsigned sh[256];
    const int t = threadIdx.x;
    const int base = blockIdx.x * 1024 + t * 4;
    unsigned v0 = (base + 0 < n) ? deg[base + 0] : 0u;
    unsigned v1 = (base + 1 < n) ? deg[base + 1] : 0u;
    unsigned v2 = (base + 2 < n) ? deg[base + 2] : 0u;
    unsigned v3 = (base + 3 < n) ? deg[base + 3] : 0u;
    const unsigned s = v0 + v1 + v2 + v3;
    sh[t] = s;
    __syncthreads();
    for (int off = 1; off < 256; off <<= 1) {
        unsigned x = 0;
        if (t >= off) x = sh[t - off];
        __syncthreads();
        if (t >= off) sh[t] += x;
        __syncthreads();
    }
    const unsigned ebase = sh[t] - s;
    if (base + 0 < n) excl[base + 0] = ebase;
    if (base + 1 < n) excl[base + 1] = ebase + v0;
    if (base + 2 < n) excl[base + 2] = ebase + v0 + v1;
    if (base + 3 < n) excl[base + 3] = ebase + v0 + v1 + v2;
    if (t == 255) bsum[blockIdx.x] = sh[255];
}

__global__ void k_scan2(unsigned* __restrict__ bsum, int nb) {
    __shared__ unsigned sh[256];
    const int t = threadIdx.x;
    const unsigned v = (t < nb) ? bsum[t] : 0u;
    sh[t] = v;
    __syncthreads();
    for (int off = 1; off < 256; off <<= 1) {
        unsigned x = 0;
        if (t >= off) x = sh[t - off];
        __syncthreads();
        if (t >= off) sh[t] += x;
        __syncthreads();
    }
    if (t < nb) bsum[t] = sh[t] - v;  // exclusive
}

__global__ void k_scan3(unsigned* __restrict__ excl, const unsigned* __restrict__ bsum, int n) {
    const int t = threadIdx.x;
    const int base = blockIdx.x * 1024 + t * 4;
    const unsigned add = bsum[blockIdx.x];
#pragma unroll
    for (int j = 0; j < 4; ++j)
        if (base + j < n) excl[base + j] += add;
}

__global__ void k_scatter(const int* __restrict__ ei, unsigned* __restrict__ cursor,
                          int* __restrict__ eperm, int E) {
    const int e = blockIdx.x * 256 + threadIdx.x;
    if (e < E) {
        const unsigned pos = atomicAdd(cursor + ei[E + e], 1u);
        eperm[pos] = e;
    }
}

// ---------------- input net stage 1: h = GELU(LN(x@W1+b1)) ----------------
__global__ void k_in1(const float* __restrict__ x, const float* __restrict__ W1,
                      const float* __restrict__ b1, const float* __restrict__ g1,
                      const float* __restrict__ bn1, float* __restrict__ h, int n) {
    const int t = threadIdx.x, lane = t & 63, wave = t >> 6;
    const int d0 = lane << 1;
    const float2 w0 = *(const float2*)(W1 + d0);
    const float2 w1 = *(const float2*)(W1 + 128 + d0);
    const float2 w2 = *(const float2*)(W1 + 256 + d0);
    const float2 w3 = *(const float2*)(W1 + 384 + d0);
    const float2 bb = *(const float2*)(b1 + d0);
    const float2 gg = *(const float2*)(g1 + d0);
    const float2 nn = *(const float2*)(bn1 + d0);
    const int stride = gridDim.x * 4;
    for (int node = blockIdx.x * 4 + wave; node < n; node += stride) {
        const float4 xv = *(const float4*)(x + (size_t)node * 4);
        float h0 = bb.x + xv.x * w0.x + xv.y * w1.x + xv.z * w2.x + xv.w * w3.x;
        float h1 = bb.y + xv.x * w0.y + xv.y * w1.y + xv.z * w2.y + xv.w * w3.y;
        const float s = wred64(h0 + h1), q = wred64(h0 * h0 + h1 * h1);
        const float mean = s * 0.0078125f, var = q * 0.0078125f - mean * mean;
        const float rs = rsqrtf(var + 1e-5f);
        h0 = geluf((h0 - mean) * rs * gg.x + nn.x);
        h1 = geluf((h1 - mean) * rs * gg.y + nn.y);
        *(float2*)(h + (size_t)node * 128 + d0) = make_float2(h0, h1);
    }
}

// ---------------- input net stage 2: xcur = LN(h@W2+b2, g2, bn2) ----------------
__global__ __launch_bounds__(256, 2) void k_in2(const float* __restrict__ A,
                                                const float* __restrict__ W,
                                                const float* __restrict__ bias,
                                                const float* __restrict__ g,
                                                const float* __restrict__ b,
                                                float* __restrict__ C, int n) {
    __shared__ float As[64 * 132];
    __shared__ float Ws[4096];
    const int t = threadIdx.x;
    const int n0 = blockIdx.x * 64;
    {
        const int r = t >> 2, c0 = (t & 3) << 5;
        const int row = n0 + r;
        const bool ok = row < n;
#pragma unroll
        for (int j = 0; j < 8; ++j) {
            const int col = c0 + (j << 2);
            float4 v = make_float4(0.f, 0.f, 0.f, 0.f);
            if (ok) v = *(const float4*)(A + (size_t)row * 128 + col);
            *(float4*)(As + r * 132 + col) = v;
        }
    }
    float acc[4][8];
#pragma unroll
    for (int r = 0; r < 4; ++r)
#pragma unroll
        for (int o = 0; o < 8; ++o) acc[r][o] = 0.f;
    const int og = t & 15, eg = t >> 4;
    const int ogc = og << 2, r0 = eg << 2;
#pragma unroll
    for (int q4 = 0; q4 < 4; ++q4) {
        stage_wq(Ws, W + q4 * 4096, t);
        __syncthreads();
        kloop_q(As, Ws, acc, r0, ogc, q4 * 32);
        __syncthreads();
    }
    const float4 bA = *(const float4*)(bias + ogc);
    const float4 bB = *(const float4*)(bias + 64 + ogc);
    const float4 gA = *(const float4*)(g + ogc);
    const float4 gB = *(const float4*)(g + 64 + ogc);
    const float4 lA = *(const float4*)(b + ogc);
    const float4 lB = *(const float4*)(b + 64 + ogc);
#pragma unroll
    for (int r = 0; r < 4; ++r) {
        float v[8];
        v[0] = acc[r][0] + bA.x; v[1] = acc[r][1] + bA.y;
        v[2] = acc[r][2] + bA.z; v[3] = acc[r][3] + bA.w;
        v[4] = acc[r][4] + bB.x; v[5] = acc[r][5] + bB.y;
        v[6] = acc[r][6] + bB.z; v[7] = acc[r][7] + bB.w;
        float s = 0.f, q = 0.f;
#pragma unroll
        for (int o = 0; o < 8; ++o) { s += v[o]; q += v[o] * v[o]; }
#pragma unroll
        for (int m = 1; m < 16; m <<= 1) { s += __shfl_xor(s, m); q += __shfl_xor(q, m); }
        const float mean = s * 0.0078125f;
        const float var = q * 0.0078125f - mean * mean;
        const float rs = rsqrtf(var + 1e-5f);
        const int row = n0 + r0 + r;
        if (row < n) {
            *(float4*)(C + (size_t)row * 128 + ogc) = make_float4(
                (v[0] - mean) * rs * gA.x + lA.x, (v[1] - mean) * rs * gA.y + lA.y,
                (v[2] - mean) * rs * gA.z + lA.z, (v[3] - mean) * rs * gA.w + lA.w);
            *(float4*)(C + (size_t)row * 128 + 64 + ogc) = make_float4(
                (v[4] - mean) * rs * gB.x + lB.x, (v[5] - mean) * rs * gB.y + lB.y,
                (v[6] - mean) * rs * gB.z + lB.z, (v[7] - mean) * rs * gB.w + lB.w);
        }
    }
}

// ---------------- node-wise LayerNorm ----------------
__global__ void k_ln(const float* __restrict__ in, const float* __restrict__ g,
                     const float* __restrict__ b, float* __restrict__ out, int n) {
    const int t = threadIdx.x, lane = t & 63, wave = t >> 6;
    const int d0 = lane << 1;
    const float ga = g[d0], gb = g[d0 + 1], ba = b[d0], bb = b[d0 + 1];
    const int stride = gridDim.x * 4;
    for (int node = blockIdx.x * 4 + wave; node < n; node += stride) {
        const float2 v = *(const float2*)(in + (size_t)node * 128 + d0);
        const float s = wred64(v.x + v.y), q = wred64(v.x * v.x + v.y * v.y);
        const float mean = s * 0.0078125f, var = q * 0.0078125f - mean * mean;
        const float rs = rsqrtf(var + 1e-5f);
        *(float2*)(out + (size_t)node * 128 + d0) =
            make_float2((v.x - mean) * rs * ga + ba, (v.y - mean) * rs * gb + bb);
    }
}

// ---------------- Wx / Wj precompute ----------------
__global__ void k_wxj(const float* __restrict__ c, float* __restrict__ Wx,
                      float* __restrict__ Wj) {
    const int idx = blockIdx.x * 256 + threadIdx.x;  // < 16384
    const float a = c[idx], b = c[16384 + idx];
    Wx[idx] = a - b;
    Wj[idx] = b;
}

// ---------------- fill aggregation buffers ----------------
__global__ void k_fill(unsigned* __restrict__ amax, float* __restrict__ asum, int n4) {
    const uint4 mneg = make_uint4(MAPNEGINF, MAPNEGINF, MAPNEGINF, MAPNEGINF);
    const float4 z = make_float4(0.f, 0.f, 0.f, 0.f);
    for (int i = blockIdx.x * blockDim.x + threadIdx.x; i < n4; i += gridDim.x * blockDim.x) {
        ((uint4*)amax)[i] = mneg;
        ((float4*)asum)[i] = z;
    }
}

// ---------------- P/Q: fused pre-LN + dual GEMM ----------------
__global__ __launch_bounds__(256, 2) void k_pq(const float* __restrict__ xcur,
                                               const float* __restrict__ g,
                                               const float* __restrict__ b,
                                               const float* __restrict__ Wx,
                                               const float* __restrict__ Wj,
                                               const float* __restrict__ cb1,
                                               float* __restrict__ P, float* __restrict__ Q,
                                               int n) {
    __shared__ float As[64 * 132];
    __shared__ float Ws[4096];
    __shared__ float sg[128], sb[128];
    const int t = threadIdx.x;
    const int n0 = blockIdx.x * 64;
    if (t < 128) { sg[t] = g[t]; sb[t] = b[t]; }
    __syncthreads();
    {
        const int r = t >> 2, c0 = (t & 3) << 5;
        const int row = n0 + r;
        const bool ok = row < n;
        float4 v4[8];
        float s = 0.f, q = 0.f;
        if (ok) {
#pragma unroll
            for (int j = 0; j < 8; ++j) {
                v4[j] = *(const float4*)(xcur + (size_t)row * 128 + c0 + (j << 2));
                s += v4[j].x + v4[j].y + v4[j].z + v4[j].w;
                q += v4[j].x * v4[j].x + v4[j].y * v4[j].y + v4[j].z * v4[j].z +
                     v4[j].w * v4[j].w;
            }
        } else {
#pragma unroll
            for (int j = 0; j < 8; ++j) v4[j] = make_float4(0.f, 0.f, 0.f, 0.f);
        }
        s += __shfl_xor(s, 1); s += __shfl_xor(s, 2);
        q += __shfl_xor(q, 1); q += __shfl_xor(q, 2);
        const float mean = s * 0.0078125f;
        const float var = q * 0.0078125f - mean * mean;
        const float rs = rsqrtf(var + 1e-5f);
#pragma unroll
        for (int j = 0; j < 8; ++j) {
            const int c = c0 + (j << 2);
            As[r * 132 + c + 0] = (v4[j].x - mean) * rs * sg[c + 0] + sb[c + 0];
            As[r * 132 + c + 1] = (v4[j].y - mean) * rs * sg[c + 1] + sb[c + 1];
            As[r * 132 + c + 2] = (v4[j].z - mean) * rs * sg[c + 2] + sb[c + 2];
            As[r * 132 + c + 3] = (v4[j].w - mean) * rs * sg[c + 3] + sb[c + 3];
        }
    }
    float accP[4][8], accQ[4][8];
#pragma unroll
    for (int r = 0; r < 4; ++r)
#pragma unroll
        for (int o = 0; o < 8; ++o) { accP[r][o] = 0.f; accQ[r][o] = 0.f; }
    const int og = t & 15, eg = t >> 4;
    const int ogc = og << 2, r0 = eg << 2;
#pragma unroll
    for (int q4 = 0; q4 < 4; ++q4) {
        stage_wq(Ws, Wx + q4 * 4096, t);
        __syncthreads();
        kloop_q(As, Ws, accP, r0, ogc, q4 * 32);
        __syncthreads();
    }
#pragma unroll
    for (int q4 = 0; q4 < 4; ++q4) {
        stage_wq(Ws, Wj + q4 * 4096, t);
        __syncthreads();
        kloop_q(As, Ws, accQ, r0, ogc, q4 * 32);
        __syncthreads();
    }
    const float4 bA = *(const float4*)(cb1 + ogc);
    const float4 bB = *(const float4*)(cb1 + 64 + ogc);
#pragma unroll
    for (int r = 0; r < 4; ++r) {
        const int row = n0 + r0 + r;
        if (row < n) {
            *(float4*)(P + (size_t)row * 128 + ogc) =
                make_float4(accP[r][0] + bA.x, accP[r][1] + bA.y, accP[r][2] + bA.z,
                            accP[r][3] + bA.w);
            *(float4*)(P + (size_t)row * 128 + 64 + ogc) =
                make_float4(accP[r][4] + bB.x, accP[r][5] + bB.y, accP[r][6] + bB.z,
                            accP[r][7] + bB.w);
            *(float4*)(Q + (size_t)row * 128 + ogc) =
                make_float4(accQ[r][0], accQ[r][1], accQ[r][2], accQ[r][3]);
            *(float4*)(Q + (size_t)row * 128 + 64 + ogc) =
                make_float4(accQ[r][4], accQ[r][5], accQ[r][6], accQ[r][7]);
        }
    }
}

// ---------------- fused edge conv ----------------
__global__ __launch_bounds__(256, 2) void k_edge(
    const float* __restrict__ P, const float* __restrict__ Q, const int* __restrict__ ei,
    const int* __restrict__ eperm, const float* __restrict__ W2, const float* __restrict__ g1,
    const float* __restrict__ b1, const float* __restrict__ cb2, const float* __restrict__ g2,
    const float* __restrict__ b2, unsigned* __restrict__ amax, float* __restrict__ asum, int E) {
    __shared__ float Us[64 * 132];
    __shared__ float Ws[4096];
    __shared__ int sdst[64], ssrc[64], sdg[64];
    __shared__ float scb2[128], sg2[128], sb2[128];
    const int t = threadIdx.x;
    const int base = blockIdx.x * 64;
    if (base >= E) return;
    if (t < 64) {
        const int idx = base + t;
        const int e = eperm[idx < E ? idx : (E - 1)];
        ssrc[t] = ei[e];
        const int d = ei[E + e];
        sdg[t] = d;
        sdst[t] = (idx < E) ? d : -1;
    }
    if (t >= 128) {
        const int d = t - 128;
        scb2[d] = cb2[d];
        sg2[d] = g2[d];
        sb2[d] = b2[d];
    }
    __syncthreads();
    // Phase A: U rows = GELU(LN(P[dst]+Q[src], g1, b1))
    const int lane = t & 63, wave = t >> 6;
    const int d0 = lane << 1;
    const float g1a = g1[d0], g1b = g1[d0 + 1], b1a = b1[d0], b1b = b1[d0 + 1];
#pragma unroll 2
    for (int p = 0; p < 16; ++p) {
        const int i = (p << 2) + wave;
        const int nd = sdg[i], ns = ssrc[i];
        const float2 pv = *(const float2*)(P + (size_t)nd * 128 + d0);
        const float2 qv = *(const float2*)(Q + (size_t)ns * 128 + d0);
        const float x0 = pv.x + qv.x, x1 = pv.y + qv.y;
        const float s = wred64(x0 + x1);
        const float q = wred64(x0 * x0 + x1 * x1);
        const float mean = s * 0.0078125f;
        const float var = q * 0.0078125f - mean * mean;
        const float rs = rsqrtf(var + 1e-5f);
        const float y0 = geluf((x0 - mean) * rs * g1a + b1a);
        const float y1 = geluf((x1 - mean) * rs * g1b + b1b);
        *(float2*)(Us + i * 132 + d0) = make_float2(y0, y1);
    }
    // GEMM2: M2 = U @ cW2
    float acc[4][8];
#pragma unroll
    for (int r = 0; r < 4; ++r)
#pragma unroll
        for (int o = 0; o < 8; ++o) acc[r][o] = 0.f;
    const int og = t & 15, eg = t >> 4;
    const int ogc = og << 2, r0 = eg << 2;
#pragma unroll
    for (int q4 = 0; q4 < 4; ++q4) {
        stage_wq(Ws, W2 + q4 * 4096, t);
        __syncthreads();
        kloop_q(Us, Ws, acc, r0, ogc, q4 * 32);
        __syncthreads();
    }
    // epilogue: +cb2, row LN over 16 lanes, GELU, write back to Us
#pragma unroll
    for (int r = 0; r < 4; ++r) {
        float v[8];
        float s = 0.f, q = 0.f;
#pragma unroll
        for (int o = 0; o < 8; ++o) {
            const int col = (o < 4) ? (ogc + o) : (64 + ogc + o - 4);
            v[o] = acc[r][o] + scb2[col];
            s += v[o];
            q += v[o] * v[o];
        }
#pragma unroll
        for (int m = 1; m < 16; m <<= 1) { s += __shfl_xor(s, m); q += __shfl_xor(q, m); }
        const float mean = s * 0.0078125f;
        const float var = q * 0.0078125f - mean * mean;
        const float rs = rsqrtf(var + 1e-5f);
#pragma unroll
        for (int o = 0; o < 8; ++o) {
            const int col = (o < 4) ? (ogc + o) : (64 + ogc + o - 4);
            v[o] = geluf((v[o] - mean) * rs * sg2[col] + sb2[col]);
        }
        *(float4*)(Us + (r0 + r) * 132 + ogc) = make_float4(v[0], v[1], v[2], v[3]);
        *(float4*)(Us + (r0 + r) * 132 + 64 + ogc) = make_float4(v[4], v[5], v[6], v[7]);
    }
    __syncthreads();
    // Phase C: run-length segmented max/sum (edges dst-sorted)
    if (t < 128) {
        int cur = sdst[0];
        float vmax = -INFINITY, vsum = 0.f;
        for (int i = 0; i < 64; ++i) {
            const int dn = sdst[i];
            if (dn != cur) {
                if (cur >= 0) {
                    atomicMax(amax + (size_t)cur * 128 + t, fmap(vmax));
                    atomicAdd(asum + (size_t)cur * 128 + t, vsum);
                }
                cur = dn;
                vmax = -INFINITY;
                vsum = 0.f;
            }
            const float v = Us[i * 132 + t];
            vmax = fmaxf(vmax, v);
            vsum += v;
        }
        if (cur >= 0) {
            atomicMax(amax + (size_t)cur * 128 + t, fmap(vmax));
            atomicAdd(asum + (size_t)cur * 128 + t, vsum);
        }
    }
}

// ---------------- update: xcur += [amax, amean] @ pW + pb ----------------
__global__ __launch_bounds__(256, 2) void k_update(const unsigned* __restrict__ amax,
                                                   const float* __restrict__ asum,
                                                   const unsigned* __restrict__ deg,
                                                   const float* __restrict__ pW,
                                                   const float* __restrict__ pb,
                                                   float* __restrict__ xcur, int n) {
    __shared__ float As[64 * 132];
    __shared__ float Ws[4096];
    const int t = threadIdx.x;
    const int n0 = blockIdx.x * 64;
    const int og = t & 15, eg = t >> 4;
    const int ogc = og << 2, r0 = eg << 2;
    float acc[4][8];
#pragma unroll
    for (int r = 0; r < 4; ++r)
#pragma unroll
        for (int o = 0; o < 8; ++o) acc[r][o] = 0.f;
    const int r = t >> 2, c0 = (t & 3) << 5;
    const int row = n0 + r;
    const bool ok = row < n;
#pragma unroll
    for (int pass = 0; pass < 2; ++pass) {
        if (pass == 0) {
#pragma unroll
            for (int j = 0; j < 8; ++j) {
                const int col = c0 + (j << 2);
                float4 v = make_float4(0.f, 0.f, 0.f, 0.f);
                if (ok) {
                    const uint4 u = *(const uint4*)(amax + (size_t)row * 128 + col);
                    v.x = (u.x == MAPNEGINF) ? 0.f : funmap(u.x);
                    v.y = (u.y == MAPNEGINF) ? 0.f : funmap(u.y);
                    v.z = (u.z == MAPNEGINF) ? 0.f : funmap(u.z);
                    v.w = (u.w == MAPNEGINF) ? 0.f : funmap(u.w);
                }
                *(float4*)(As + r * 132 + col) = v;
            }
        } else {
            float inv = 0.f;
            if (ok) {
                const unsigned dv = deg[row];
                inv = 1.f / (float)(dv < 1u ? 1u : dv);
            }
#pragma unroll
            for (int j = 0; j < 8; ++j) {
                const int col = c0 + (j << 2);
                float4 v = make_float4(0.f, 0.f, 0.f, 0.f);
                if (ok) {
                    const float4 sv = *(const float4*)(asum + (size_t)row * 128 + col);
                    v = make_float4(sv.x * inv, sv.y * inv, sv.z * inv, sv.w * inv);
                }
                *(float4*)(As + r * 132 + col) = v;
            }
        }
#pragma unroll
        for (int q4 = 0; q4 < 4; ++q4) {
            stage_wq(Ws, pW + (size_t)(pass * 128 + q4 * 32) * 128, t);
            __syncthreads();
            kloop_q(As, Ws, acc, r0, ogc, q4 * 32);
            __syncthreads();
        }
    }
    const float4 bA = *(const float4*)(pb + ogc);
    const float4 bB = *(const float4*)(pb + 64 + ogc);
#pragma unroll
    for (int rr = 0; rr < 4; ++rr) {
        const int orow = n0 + r0 + rr;
        if (orow < n) {
            const float4 x0 = *(const float4*)(xcur + (size_t)orow * 128 + ogc);
            const float4 x1 = *(const float4*)(xcur + (size_t)orow * 128 + 64 + ogc);
            *(float4*)(xcur + (size_t)orow * 128 + ogc) =
                make_float4(x0.x + acc[rr][0] + bA.x, x0.y + acc[rr][1] + bA.y,
                            x0.z + acc[rr][2] + bA.z, x0.w + acc[rr][3] + bA.w);
            *(float4*)(xcur + (size_t)orow * 128 + 64 + ogc) =
                make_float4(x1.x + acc[rr][4] + bB.x, x1.y + acc[rr][5] + bB.y,
                            x1.z + acc[rr][6] + bB.z, x1.w + acc[rr][7] + bB.w);
        }
    }
}

// ---------------- graph pooling ----------------
__global__ void k_pool_init(unsigned* __restrict__ gmax1, float* __restrict__ gsum1,
                            unsigned* __restrict__ gcount1, unsigned* __restrict__ gmax2,
                            float* __restrict__ gsum2, unsigned* __restrict__ gcount2, int ng) {
    const int i = blockIdx.x * 256 + threadIdx.x;
    if (i < ng * 128) {
        gmax1[i] = MAPNEGINF;
        gsum1[i] = 0.f;
        gmax2[i] = MAPNEGINF;
        gsum2[i] = 0.f;
    }
    if (i < ng) {
        gcount1[i] = 0u;
        gcount2[i] = 0u;
    }
}

__global__ void k_pool(const float* __restrict__ in, const int* __restrict__ batch,
                       unsigned* __restrict__ gmax, float* __restrict__ gsum,
                       unsigned* __restrict__ gcount, int n) {
    const int t = threadIdx.x;
    if (t >= 128) return;
    const int per = (n + gridDim.x - 1) / gridDim.x;
    const int i0 = blockIdx.x * per;
    const int i1 = min(n, i0 + per);
    if (i0 >= i1) return;
    int cur = batch[i0];
    float vmax = -INFINITY, vsum = 0.f;
    unsigned cnt = 0;
    for (int i = i0; i < i1; ++i) {
        const int g = batch[i];
        if (g != cur) {
            atomicMax(gmax + (size_t)cur * 128 + t, fmap(vmax));
            atomicAdd(gsum + (size_t)cur * 128 + t, vsum);
            if (t == 0) atomicAdd(gcount + cur, cnt);
            cur = g;
            vmax = -INFINITY;
            vsum = 0.f;
            cnt = 0;
        }
        const float v = in[(size_t)i * 128 + t];
        vmax = fmaxf(vmax, v);
        vsum += v;
        cnt++;
    }
    atomicMax(gmax + (size_t)cur * 128 + t, fmap(vmax));
    atomicAdd(gsum + (size_t)cur * 128 + t, vsum);
    if (t == 0) atomicAdd(gcount + cur, cnt);
}

__global__ void k_xp(const unsigned* __restrict__ gmax1, const float* __restrict__ gsum1,
                     const unsigned* __restrict__ gcount1, const unsigned* __restrict__ gmax2,
                     const float* __restrict__ gsum2, const unsigned* __restrict__ gcount2,
                     float* __restrict__ xp) {
    const int g = blockIdx.x, d = threadIdx.x;
    const unsigned c1u = gcount1[g], c2u = gcount2[g];
    const float c1 = (float)(c1u < 1u ? 1u : c1u);
    const float c2 = (float)(c2u < 1u ? 1u : c2u);
    const unsigned m1 = gmax1[g * 128 + d], m2 = gmax2[g * 128 + d];
    xp[g * 512 + d] = (m1 == MAPNEGINF) ? 0.f : funmap(m1);
    xp[g * 512 + 128 + d] = gsum1[g * 128 + d] / c1;
    xp[g * 512 + 256 + d] = (m2 == MAPNEGINF) ? 0.f : funmap(m2);
    xp[g * 512 + 384 + d] = gsum2[g * 128 + d] / c2;
}

// ---------------- knowledge MLP (tiny) ----------------
__global__ __launch_bounds__(64) void k_know(
    const float* __restrict__ xp, const float* __restrict__ kW1, const float* __restrict__ kb1,
    const float* __restrict__ kg1, const float* __restrict__ kbb1, const float* __restrict__ kW2,
    const float* __restrict__ kb2, const float* __restrict__ kg2, const float* __restrict__ kbb2,
    const float* __restrict__ kW3, const float* __restrict__ kb3, const float* __restrict__ kg3,
    const float* __restrict__ kbb3, const float* __restrict__ kW4, const float* __restrict__ kb4,
    float* __restrict__ out) {
    __shared__ float sh[512];
    __shared__ float s3[32];
    const int l = threadIdx.x, g = blockIdx.x;
    const int d0 = l << 1;
    *(float4*)(sh + l * 8) = *(const float4*)(xp + g * 512 + l * 8);
    *(float4*)(sh + l * 8 + 4) = *(const float4*)(xp + g * 512 + l * 8 + 4);
    __syncthreads();
    float a0 = kb1[d0], a1 = kb1[d0 + 1];
    for (int k = 0; k < 512; ++k) {
        const float u = sh[k];
        const float2 w = *(const float2*)(kW1 + k * 128 + d0);
        a0 += u * w.x;
        a1 += u * w.y;
    }
    {
        const float s = wred64(a0 + a1), q = wred64(a0 * a0 + a1 * a1);
        const float mean = s * 0.0078125f, var = q * 0.0078125f - mean * mean;
        const float rs = rsqrtf(var + 1e-5f);
        a0 = geluf((a0 - mean) * rs * kg1[d0] + kbb1[d0]);
        a1 = geluf((a1 - mean) * rs * kg1[d0 + 1] + kbb1[d0 + 1]);
    }
    __syncthreads();
    sh[d0] = a0;
    sh[d0 + 1] = a1;
    __syncthreads();
    float b0v = kb2[d0], b1v = kb2[d0 + 1];
    for (int k = 0; k < 128; ++k) {
        const float u = sh[k];
        const float2 w = *(const float2*)(kW2 + k * 128 + d0);
        b0v += u * w.x;
        b1v += u * w.y;
    }
    {
        const float s = wred64(b0v + b1v), q = wred64(b0v * b0v + b1v * b1v);
        const float mean = s * 0.0078125f, var = q * 0.0078125f - mean * mean;
        const float rs = rsqrtf(var + 1e-5f);
        b0v = geluf((b0v - mean) * rs * kg2[d0] + kbb2[d0]);
        b1v = geluf((b1v - mean) * rs * kg2[d0 + 1] + kbb2[d0 + 1]);
    }
    __syncthreads();
    sh[d0] = b0v;
    sh[d0 + 1] = b1v;
    __syncthreads();
    const int d3 = (l & 15) << 1;
    float c0 = kb3[d3], c1 = kb3[d3 + 1];
    for (int k = 0; k < 128; ++k) {
        const float u = sh[k];
        const float2 w = *(const float2*)(kW3 + k * 32 + d3);
        c0 += u * w.x;
        c1 += u * w.y;
    }
    {
        float s = c0 + c1, q = c0 * c0 + c1 * c1;
#pragma unroll
        for (int m = 1; m < 16; m <<= 1) {
            s += __shfl_xor(s, m);
            q += __shfl_xor(q, m);
        }
        const float mean = s * 0.03125f, var = q * 0.03125f - mean * mean;
        const float rs = rsqrtf(var + 1e-5f);
        c0 = geluf((c0 - mean) * rs * kg3[d3] + kbb3[d3]);
        c1 = geluf((c1 - mean) * rs * kg3[d3 + 1] + kbb3[d3 + 1]);
    }
    if (l < 16) {
        s3[d3] = c0;
        s3[d3 + 1] = c1;
    }
    __syncthreads();
    if (l == 0) {
        float rr = kb4[0];
        for (int k = 0; k < 32; ++k) rr += s3[k] * kW4[k];
        out[g] = rr;
    }
}

// ---------------- host launch ----------------
extern "C" void kernel_launch(void* const* d_in, const int* in_sizes, int n_in, void* d_out,
                              int out_size, void* d_ws, size_t ws_size, hipStream_t stream) {
    const int N = in_sizes[0] / 4;
    const int E = in_sizes[1] / 2;
    const int G = 64;
    const int L = 4;

    const float* x = (const float*)d_in[0];
    const int* ei = (const int*)d_in[1];
    const int* batch = (const int*)d_in[2];
    const float* inW1 = (const float*)d_in[4];
    const float* inb1 = (const float*)d_in[5];
    const float* ing1 = (const float*)d_in[6];
    const float* inbn1 = (const float*)d_in[7];
    const float* inW2 = (const float*)d_in[8];
    const float* inb2 = (const float*)d_in[9];
    const float* ing2 = (const float*)d_in[10];
    const float* inbn2 = (const float*)d_in[11];
    const float* pre_g = (const float*)d_in[12];
    const float* pre_b = (const float*)d_in[13];
    const float* cW1 = (const float*)d_in[14];
    const float* cb1 = (const float*)d_in[15];
    const float* cg1 = (const float*)d_in[16];
    const float* cbb1 = (const float*)d_in[17];
    const float* cW2 = (const float*)d_in[18];
    const float* cb2 = (const float*)d_in[19];
    const float* cg2 = (const float*)d_in[20];
    const float* cbb2 = (const float*)d_in[21];
    const float* pW = (const float*)d_in[22];
    const float* pb = (const float*)d_in[23];
    const float* ag_g = (const float*)d_in[24];
    const float* ag_b = (const float*)d_in[25];
    const float* kW1 = (const float*)d_in[26];
    const float* kb1 = (const float*)d_in[27];
    const float* kg1 = (const float*)d_in[28];
    const float* kbb1 = (const float*)d_in[29];
    const float* kW2 = (const float*)d_in[30];
    const float* kb2 = (const float*)d_in[31];
    const float* kg2 = (const float*)d_in[32];
    const float* kbb2 = (const float*)d_in[33];
    const float* kW3 = (const float*)d_in[34];
    const float* kb3 = (const float*)d_in[35];
    const float* kg3 = (const float*)d_in[36];
    const float* kbb3 = (const float*)d_in[37];
    const float* kW4 = (const float*)d_in[38];
    const float* kb4 = (const float*)d_in[39];
    float* out = (float*)d_out;

    char* wsb = (char*)d_ws;
    size_t off = 0;
    auto ALC = [&](size_t bytes) {
        void* p = wsb + off;
        off = (off + bytes + 255) & ~(size_t)255;
        return p;
    };
    const size_t NB = (size_t)N * 128 * 4;
    float* xcur = (float*)ALC(NB);
    float* Pb = (float*)ALC(NB);
    float* Qb = (float*)ALC(NB);
    unsigned* amax = (unsigned*)ALC(NB);
    float* asum = (float*)ALC(NB);
    unsigned* deg = (unsigned*)ALC((size_t)N * 4);
    unsigned* cursor = (unsigned*)ALC((size_t)N * 4);
    unsigned* bsum = (unsigned*)ALC(4096);
    int* eperm = (int*)ALC((size_t)E * 4);
    float* Wx = (float*)ALC(65536);
    float* Wj = (float*)ALC(65536);
    unsigned* gmax1 = (unsigned*)ALC((size_t)G * 128 * 4);
    float* gsum1 = (float*)ALC((size_t)G * 128 * 4);
    unsigned* gcount1 = (unsigned*)ALC((size_t)G * 4);
    unsigned* gmax2 = (unsigned*)ALC((size_t)G * 128 * 4);
    float* gsum2 = (float*)ALC((size_t)G * 128 * 4);
    unsigned* gcount2 = (unsigned*)ALC((size_t)G * 4);
    float* xp = (float*)ALC((size_t)G * 512 * 4);

    if (off > ws_size) {
        // Diagnostic fallback: workspace too small -> zero output, no faults.
        k_zero<<<(out_size + 255) / 256, 256, 0, stream>>>((unsigned*)d_out, out_size);
        return;
    }

    // --- CSR-style dst-sorted edge permutation ---
    k_zero<<<(N + 255) / 256, 256, 0, stream>>>(deg, N);
    k_count<<<(E + 255) / 256, 256, 0, stream>>>(ei, deg, E);
    const int nb = (N + 1023) / 1024;
    k_scan1<<<nb, 256, 0, stream>>>(deg, cursor, bsum, N);
    k_scan2<<<1, 256, 0, stream>>>(bsum, nb);
    k_scan3<<<nb, 256, 0, stream>>>(cursor, bsum, N);
    k_scatter<<<(E + 255) / 256, 256, 0, stream>>>(ei, cursor, eperm, E);

    // --- input net + first pooling ---
    const int gemmGrid = (N + 63) / 64;
    k_in1<<<1024, 256, 0, stream>>>(x, inW1, inb1, ing1, inbn1, Pb, N);
    k_in2<<<gemmGrid, 256, 0, stream>>>(Pb, inW2, inb2, ing2, inbn2, xcur, N);
    k_pool_init<<<(G * 128 + 255) / 256, 256, 0, stream>>>(gmax1, gsum1, gcount1, gmax2, gsum2,
                                                           gcount2, G);
    k_pool<<<512, 256, 0, stream>>>(xcur, batch, gmax1, gsum1, gcount1, N);

    // --- edge conv layers ---
    for (int l = 0; l < L; ++l) {
        k_wxj<<<64, 256, 0, stream>>>(cW1 + (size_t)l * 32768, Wx, Wj);
        k_pq<<<gemmGrid, 256, 0, stream>>>(xcur, pre_g + l * 128, pre_b + l * 128, Wx, Wj,
                                           cb1 + l * 128, Pb, Qb, N);
        k_fill<<<2048, 256, 0, stream>>>(amax, asum, N * 32);
        k_edge<<<(E + 63) / 64, 256, 0, stream>>>(Pb, Qb, ei, eperm, cW2 + (size_t)l * 16384,
                                                  cg1 + l * 128, cbb1 + l * 128, cb2 + l * 128,
                                                  cg2 + l * 128, cbb2 + l * 128, amax, asum, E);
        k_update<<<gemmGrid, 256, 0, stream>>>(amax, asum, deg, pW + (size_t)l * 32768,
                                               pb + l * 128, xcur, N);
    }

    // --- final LN + pooling + head ---
    k_ln<<<1024, 256, 0, stream>>>(xcur, ag_g, ag_b, Pb, N);
    k_pool<<<512, 256, 0, stream>>>(Pb, batch, gmax2, gsum2, gcount2, N);
    k_xp<<<G, 128, 0, stream>>>(gmax1, gsum1, gcount1, gmax2, gsum2, gcount2, xp);
    k_know<<<G, 64, 0, stream>>>(xp, kW1, kb1, kg1, kbb1, kW2, kb2, kg2, kbb2, kW3, kb3, kg3, kbb3,
                                 kW4, kb4, out);
}